// Round 1
// baseline (227.734 us; speedup 1.0000x reference)
//
#include <hip/hip_runtime.h>

// Problem constants (fixed by the reference setup)
#define BB   2
#define DD   96
#define HH   96
#define WW   96
#define CINC 16
#define COUTC 32
#define KVOL 27                       // 3*3*3
#define GRID_VOX (BB*DD*HH*WW)        // 1,769,472 voxels

// Workspace layout:
//   [0 .. GRID_VOX*4)            : int32 idx grid (voxel -> point id, -1 = empty)
//   [GRID_VOX*4 .. +27*16*32*4)  : repacked weights wr[kk][ci][co]
#define WR_OFFSET_BYTES (GRID_VOX * sizeof(int))   // 7,077,888 (16B aligned)

__global__ __launch_bounds__(256) void init_grid_kernel(int* __restrict__ g) {
    const int n4 = GRID_VOX / 4;
    int4 v = make_int4(-1, -1, -1, -1);
    for (int k = blockIdx.x * blockDim.x + threadIdx.x; k < n4;
         k += gridDim.x * blockDim.x) {
        ((int4*)g)[k] = v;
    }
}

__global__ __launch_bounds__(256) void scatter_idx_kernel(
        const int* __restrict__ idx, int* __restrict__ g, int n) {
    int i = blockIdx.x * blockDim.x + threadIdx.x;
    if (i >= n) return;
    int4 v = ((const int4*)idx)[i];   // (b, z, y, x)
    int lin = ((v.x * DD + v.y) * HH + v.z) * WW + v.w;
    g[lin] = i;
}

// conv_w is [co][ci][dz][dy][dx] -> wr[kk][ci][co]  (kk = dz*9+dy*3+dx)
__global__ __launch_bounds__(256) void repack_w_kernel(
        const float* __restrict__ w, float* __restrict__ wr) {
    int t = blockIdx.x * blockDim.x + threadIdx.x;  // t = kk*512 + ci*32 + co
    if (t >= KVOL * CINC * COUTC) return;
    int co = t & (COUTC - 1);
    int ci = (t >> 5) & (CINC - 1);
    int kk = t >> 9;
    wr[t] = w[(co * CINC + ci) * KVOL + kk];
}

__global__ __launch_bounds__(256) void conv_gather_kernel(
        const float*  __restrict__ feat,
        const int*    __restrict__ idx,
        const float*  __restrict__ wr,     // [27][16][32], uniform-indexed
        const float*  __restrict__ bias,   // [32]
        const int*    __restrict__ g,
        float*        __restrict__ out,
        int n) {
    int i = blockIdx.x * blockDim.x + threadIdx.x;
    if (i >= n) return;

    int4 v = ((const int4*)idx)[i];   // b, z, y, x
    const int b = v.x, z = v.y, y = v.z, x = v.w;

    float acc[COUTC];
#pragma unroll
    for (int co = 0; co < COUTC; ++co) acc[co] = bias[co];

    for (int kk = 0; kk < KVOL; ++kk) {
        // decode offset (uniform across the wave)
        int dz = kk / 9;
        int r  = kk - dz * 9;
        int dy = r / 3;
        int dx = r - dy * 3;

        int nz = z + dz - 1;
        int ny = y + dy - 1;
        int nx = x + dx - 1;
        bool inb = ((unsigned)nz < DD) & ((unsigned)ny < HH) & ((unsigned)nx < WW);

        int nid = -1;
        if (inb) nid = g[((b * DD + nz) * HH + ny) * WW + nx];

        float f[CINC];
        if (nid >= 0) {
            const float4* fp = (const float4*)(feat + (size_t)nid * CINC);
            float4 f0 = fp[0], f1 = fp[1], f2 = fp[2], f3 = fp[3];
            f[0]=f0.x;  f[1]=f0.y;  f[2]=f0.z;  f[3]=f0.w;
            f[4]=f1.x;  f[5]=f1.y;  f[6]=f1.z;  f[7]=f1.w;
            f[8]=f2.x;  f[9]=f2.y;  f[10]=f2.z; f[11]=f2.w;
            f[12]=f3.x; f[13]=f3.y; f[14]=f3.z; f[15]=f3.w;
        } else {
#pragma unroll
            for (int ci = 0; ci < CINC; ++ci) f[ci] = 0.0f;
        }

        // Unconditional FMA block; weight addresses are wave-uniform -> s_load.
        const float* wo = wr + kk * (CINC * COUTC);
#pragma unroll
        for (int ci = 0; ci < CINC; ++ci) {
            float fv = f[ci];
#pragma unroll
            for (int co = 0; co < COUTC; ++co)
                acc[co] = fmaf(fv, wo[ci * COUTC + co], acc[co]);
        }
    }

    float4* op = (float4*)(out + (size_t)i * COUTC);
#pragma unroll
    for (int q = 0; q < 8; ++q)
        op[q] = make_float4(acc[4*q], acc[4*q+1], acc[4*q+2], acc[4*q+3]);
}

extern "C" void kernel_launch(void* const* d_in, const int* in_sizes, int n_in,
                              void* d_out, int out_size, void* d_ws, size_t ws_size,
                              hipStream_t stream) {
    const float* feat  = (const float*)d_in[0];   // [N,16] fp32
    const int*   idx   = (const int*)d_in[1];     // [N,4]  int32
    const float* convw = (const float*)d_in[2];   // [32,16,3,3,3] fp32
    const float* convb = (const float*)d_in[3];   // [32] fp32
    float* out = (float*)d_out;

    const int n = in_sizes[1] / 4;                // 200000

    int*   g  = (int*)d_ws;
    float* wr = (float*)((char*)d_ws + WR_OFFSET_BYTES);

    // 1) idx grid = -1
    init_grid_kernel<<<1024, 256, 0, stream>>>(g);
    // 2) scatter point ids (also 3) repack weights — independent, same stream)
    scatter_idx_kernel<<<(n + 255) / 256, 256, 0, stream>>>(idx, g, n);
    repack_w_kernel<<<(KVOL * CINC * COUTC + 255) / 256, 256, 0, stream>>>(convw, wr);
    // 4) gather-conv
    conv_gather_kernel<<<(n + 255) / 256, 256, 0, stream>>>(
        feat, idx, wr, convb, g, out, n);
}